// Round 1
// baseline (886.691 us; speedup 1.0000x reference)
//
#include <hip/hip_runtime.h>
#include <hip/hip_bf16.h>

// ---------------- types & helpers ----------------
typedef __bf16 bf16x8 __attribute__((ext_vector_type(8)));
typedef __bf16 bf16x4 __attribute__((ext_vector_type(4)));
typedef float  f32x4  __attribute__((ext_vector_type(4)));

#define LOG2E 1.44269504088896340f

static __device__ __forceinline__ unsigned short f2bf_bits(float f) {
  unsigned u = __builtin_bit_cast(unsigned, f);
  u = u + 0x7FFFu + ((u >> 16) & 1u);   // RNE
  return (unsigned short)(u >> 16);
}
static __device__ __forceinline__ __bf16 to_bf16(float f) {
  unsigned short s = f2bf_bits(f);
  return __builtin_bit_cast(__bf16, s);
}
static __device__ __forceinline__ float fast_sigmoid(float x) {
  return __builtin_amdgcn_rcpf(1.f + __builtin_amdgcn_exp2f(-LOG2E * x));
}

// ---------------- cast f32 -> bf16 (8 segments) ----------------
struct CastSeg { const float* src; __bf16* dst; int n4; };
struct CastArgs { CastSeg s[8]; };

__global__ __launch_bounds__(256) void cast_kernel(CastArgs a) {
  CastSeg seg = a.s[blockIdx.y];
  int idx = blockIdx.x * 256 + threadIdx.x;
  int stride = gridDim.x * 256;
  const float4* src = (const float4*)seg.src;
  bf16x4* dst = (bf16x4*)seg.dst;
  for (int i = idx; i < seg.n4; i += stride) {
    float4 v = src[i];
    bf16x4 o;
    o[0] = to_bf16(v.x); o[1] = to_bf16(v.y);
    o[2] = to_bf16(v.z); o[3] = to_bf16(v.w);
    dst[i] = o;
  }
}

// ---------------- GEMM: C[M,N] = A[M,K] @ B[N,K]^T (+bias)(+resid) ----------
// block 256 thr = 4 waves (2x2), wave = 64x64 out, block = 128x128.
// grid: x = N/128 (ceil), y = M/128, z picks B0/B1 + A,C offsets.
template<typename OutT, bool BIAS, bool RESID>
__global__ __launch_bounds__(256) void gemm_bt(
    const __bf16* __restrict__ A, long long sAz,
    const __bf16* __restrict__ B0, const __bf16* __restrict__ B1,
    OutT* __restrict__ C, long long sCz, int ldc,
    int N, int K,
    const float* __restrict__ bias, const float* __restrict__ resid, int ldr)
{
  const __bf16* B = (blockIdx.z == 0) ? B0 : B1;
  A += (size_t)blockIdx.z * (size_t)sAz;
  C += (size_t)blockIdx.z * (size_t)sCz;
  int lane = threadIdx.x & 63;
  int wid  = threadIdx.x >> 6;
  int rowBase = blockIdx.y * 128 + (wid >> 1) * 64;
  int colBase = blockIdx.x * 128 + (wid & 1) * 64;
  int lr = lane & 15;
  int lk = (lane >> 4) << 3;           // k-offset within 32-chunk
  const __bf16* Ap = A + (size_t)(rowBase + lr) * K + lk;
  const __bf16* Bp[4];
  #pragma unroll
  for (int ni = 0; ni < 4; ++ni) {
    int br = colBase + ni * 16 + lr;
    if (br > N - 1) br = N - 1;        // clamp (stores masked below)
    Bp[ni] = B + (size_t)br * K + lk;
  }
  f32x4 acc[4][4] = {};
  #pragma unroll 2
  for (int k = 0; k < K; k += 32) {
    bf16x8 aF[4], bF[4];
    #pragma unroll
    for (int mi = 0; mi < 4; ++mi)
      aF[mi] = *(const bf16x8*)(Ap + (size_t)(mi * 16) * K + k);
    #pragma unroll
    for (int ni = 0; ni < 4; ++ni)
      bF[ni] = *(const bf16x8*)(Bp[ni] + k);
    #pragma unroll
    for (int mi = 0; mi < 4; ++mi)
      #pragma unroll
      for (int ni = 0; ni < 4; ++ni)
        acc[mi][ni] = __builtin_amdgcn_mfma_f32_16x16x32_bf16(aF[mi], bF[ni], acc[mi][ni], 0, 0, 0);
  }
  // C/D layout: col = lane&15, row = (lane>>4)*4 + j   [m89-verified]
  int crow = rowBase + ((lane >> 4) << 2);
  int ccol = colBase + lr;
  #pragma unroll
  for (int mi = 0; mi < 4; ++mi) {
    #pragma unroll
    for (int ni = 0; ni < 4; ++ni) {
      int c = ccol + ni * 16;
      if (c < N) {
        #pragma unroll
        for (int j = 0; j < 4; ++j) {
          int r = crow + mi * 16 + j;
          float v = acc[mi][ni][j];
          if (BIAS)  v += bias[c];
          if (RESID) v += resid[(size_t)r * ldr + c];
          if constexpr (sizeof(OutT) == 2) C[(size_t)r * ldc + c] = to_bf16(v);
          else                             C[(size_t)r * ldc + c] = v;
        }
      }
    }
  }
}

// ---------------- causal depthwise conv (both directions) + SiLU ------------
// fwd: y[t] = w0*x[t-3]+w1*x[t-2]+w2*x[t-1]+w3*x[t]
// bwd (unflipped coords): y[t] = w3*x[t]+w2*x[t+1]+w1*x[t+2]+w0*x[t+3]
__global__ __launch_bounds__(256) void conv_silu_kernel(
    const float* __restrict__ xz,     // [dir][2048][2048], xi = cols 0..1023
    const float* __restrict__ f_cw, const float* __restrict__ f_cb,
    const float* __restrict__ b_cw, const float* __restrict__ b_cb,
    float* __restrict__ xi32,         // [dir][2048][1024]
    __bf16* __restrict__ xi16)        // [dir][2048][1024]
{
  int d  = blockIdx.x * 256 + threadIdx.x;   // 0..1023
  int t0 = blockIdx.y * 128;
  int dir = blockIdx.z >> 1, b = blockIdx.z & 1;
  const float* cw = dir ? b_cw : f_cw;
  const float* cb = dir ? b_cb : f_cb;
  float w0 = cw[d*4+0], w1 = cw[d*4+1], w2 = cw[d*4+2], w3 = cw[d*4+3];
  float bias = cb[d];
  size_t rowBase = (size_t)dir * 2048 + (size_t)b * 1024;
  const float* xp = xz + rowBase * 2048 + d;
  float* o32 = xi32 + rowBase * 1024 + d;
  __bf16* o16 = xi16 + rowBase * 1024 + d;
  auto X = [&](int t) -> float {
    return (t >= 0 && t < 1024) ? xp[(size_t)t * 2048] : 0.f;
  };
  if (dir == 0) {
    float a = X(t0-3), bb = X(t0-2), c = X(t0-1);
    for (int t = t0; t < t0 + 128; ++t) {
      float cur = xp[(size_t)t * 2048];
      float v = fmaf(w0, a, fmaf(w1, bb, fmaf(w2, c, fmaf(w3, cur, bias))));
      float s = v * fast_sigmoid(v);
      o32[(size_t)t * 1024] = s;
      o16[(size_t)t * 1024] = to_bf16(s);
      a = bb; bb = c; c = cur;
    }
  } else {
    float a = X(t0), bb = X(t0+1), c = X(t0+2);
    for (int t = t0; t < t0 + 128; ++t) {
      float nx = X(t + 3);
      float v = fmaf(w3, a, fmaf(w2, bb, fmaf(w1, c, fmaf(w0, nx, bias))));
      float s = v * fast_sigmoid(v);
      o32[(size_t)t * 1024] = s;
      o16[(size_t)t * 1024] = to_bf16(s);
      a = bb; bb = c; c = nx;
    }
  }
}

// ---------------- delta = softplus(dt @ dt_w^T + dt_b) ----------------------
__global__ __launch_bounds__(256) void delta_kernel(
    const float* __restrict__ xdbl,   // [dir][2048][64], dt = cols 0..31
    const float* __restrict__ f_dtw, const float* __restrict__ f_dtb,
    const float* __restrict__ b_dtw, const float* __restrict__ b_dtb,
    float* __restrict__ delta)        // [dir][2048][1024]
{
  int d = blockIdx.x * 256 + threadIdx.x;
  int dir = blockIdx.z;
  const float* dtw = dir ? b_dtw : f_dtw;
  const float* dtb = dir ? b_dtb : f_dtb;
  float w[32];
  #pragma unroll
  for (int k = 0; k < 32; ++k) w[k] = dtw[d * 32 + k];
  float bias = dtb[d];
  int row0 = blockIdx.y * 32;
  size_t base = (size_t)dir * 2048;
  for (int r = 0; r < 32; ++r) {
    int row = row0 + r;
    const float4* xr = (const float4*)(xdbl + (base + row) * 64);
    float acc = bias;
    #pragma unroll
    for (int q = 0; q < 8; ++q) {
      float4 v = xr[q];
      acc = fmaf(w[q*4+0], v.x, acc);
      acc = fmaf(w[q*4+1], v.y, acc);
      acc = fmaf(w[q*4+2], v.z, acc);
      acc = fmaf(w[q*4+3], v.w, acc);
    }
    float m = fmaxf(acc, 0.f);
    float e = __builtin_amdgcn_exp2f(-LOG2E * fabsf(acc));
    float sp = fmaf(__builtin_amdgcn_logf(1.f + e), 1.f / LOG2E, m);
    delta[(base + row) * 1024 + d] = sp;
  }
}

// ---------------- selective scan + gating, both directions ------------------
// lane = (channel c = tid>>4, state n = tid&15); 16 channels / block.
__global__ __launch_bounds__(256) void scan_kernel(
    const float* __restrict__ delta,  // [dir][2048][1024]
    const float* __restrict__ xi32,   // [dir][2048][1024]
    const float* __restrict__ xdbl,   // [dir][2048][64]  (B: 32+n, C: 48+n)
    const float* __restrict__ xz,     // [dir][2048][2048] (z at col 1024+d)
    const float* __restrict__ f_Alog, const float* __restrict__ f_D,
    const float* __restrict__ b_Alog, const float* __restrict__ b_D,
    __bf16* __restrict__ yout)        // [dir][2048][1024]
{
  int n = threadIdx.x & 15;
  int c = threadIdx.x >> 4;
  int d = blockIdx.x * 16 + c;
  int b = blockIdx.y;
  int dir = blockIdx.z;
  const float* Alog = dir ? b_Alog : f_Alog;
  const float* Dp   = dir ? b_D   : f_D;
  // A = -exp(A_log);  As = A*log2(e) so dA = exp2(delta*As)
  float As = -__builtin_amdgcn_exp2f(LOG2E * Alog[d * 16 + n]) * LOG2E;
  float Dv = Dp[d];
  size_t base = (size_t)dir * 2048 + (size_t)b * 1024;
  constexpr int PF = 8;
  float pdel[PF], pxi[PF], pB[PF], pC[PF], pz[PF];
  auto rowOf = [&](int tau) -> size_t {
    int t = dir ? (1023 - tau) : tau;
    return base + (size_t)t;
  };
  #pragma unroll
  for (int j = 0; j < PF; ++j) {
    size_t row = rowOf(j);
    pdel[j] = delta[row * 1024 + d];
    pxi[j]  = xi32[row * 1024 + d];
    pB[j]   = xdbl[row * 64 + 32 + n];
    pC[j]   = xdbl[row * 64 + 48 + n];
    pz[j]   = xz[row * 2048 + 1024 + d];
  }
  float h = 0.f;
  for (int tb = 0; tb < 1024; tb += PF) {
    #pragma unroll
    for (int j = 0; j < PF; ++j) {
      int tau = tb + j;
      size_t row = rowOf(tau);
      float del = pdel[j], xv = pxi[j], Bv = pB[j], Cv = pC[j], zz = pz[j];
      int tn = tau + PF;
      if (tn < 1024) {                     // prefetch PF ahead
        size_t rn = rowOf(tn);
        pdel[j] = delta[rn * 1024 + d];
        pxi[j]  = xi32[rn * 1024 + d];
        pB[j]   = xdbl[rn * 64 + 32 + n];
        pC[j]   = xdbl[rn * 64 + 48 + n];
        pz[j]   = xz[rn * 2048 + 1024 + d];
      }
      float dA = __builtin_amdgcn_exp2f(del * As);
      h = fmaf(dA, h, del * Bv * xv);
      float p = h * Cv;
      // butterfly sum over the 16 states (ds_swizzle xor 1,2,4,8)
      p += __builtin_bit_cast(float, __builtin_amdgcn_ds_swizzle(__builtin_bit_cast(int, p), 0x041F));
      p += __builtin_bit_cast(float, __builtin_amdgcn_ds_swizzle(__builtin_bit_cast(int, p), 0x081F));
      p += __builtin_bit_cast(float, __builtin_amdgcn_ds_swizzle(__builtin_bit_cast(int, p), 0x101F));
      p += __builtin_bit_cast(float, __builtin_amdgcn_ds_swizzle(__builtin_bit_cast(int, p), 0x201F));
      float yv = (p + xv * Dv) * (zz * fast_sigmoid(zz));
      if (n == 0) yout[row * 1024 + d] = to_bf16(yv);
    }
  }
}

// ---------------- LayerNorm over last dim (512) -----------------------------
__global__ __launch_bounds__(256) void ln_kernel(
    const float* __restrict__ r, const float* __restrict__ g,
    const float* __restrict__ beta, float* __restrict__ out)
{
  int row = blockIdx.x;
  int tid = threadIdx.x;
  const float* rp = r + (size_t)row * 512;
  float v0 = rp[tid], v1 = rp[tid + 256];
  float s = v0 + v1;
  float q = fmaf(v0, v0, v1 * v1);
  #pragma unroll
  for (int m = 1; m < 64; m <<= 1) {
    s += __shfl_xor(s, m, 64);
    q += __shfl_xor(q, m, 64);
  }
  __shared__ float ls[4], lq[4];
  int wid = tid >> 6;
  if ((tid & 63) == 0) { ls[wid] = s; lq[wid] = q; }
  __syncthreads();
  s = ls[0] + ls[1] + ls[2] + ls[3];
  q = lq[0] + lq[1] + lq[2] + lq[3];
  float mu = s * (1.f / 512.f);
  float var = q * (1.f / 512.f) - mu * mu;
  float rs = rsqrtf(var + 1e-5f);
  float* op = out + (size_t)row * 512;
  op[tid]       = (v0 - mu) * rs * g[tid]       + beta[tid];
  op[tid + 256] = (v1 - mu) * rs * g[tid + 256] + beta[tid + 256];
}

// ---------------- host launch ----------------
extern "C" void kernel_launch(void* const* d_in, const int* in_sizes, int n_in,
                              void* d_out, int out_size, void* d_ws, size_t ws_size,
                              hipStream_t stream)
{
  // setup_inputs() dict order
  const float* x        = (const float*)d_in[0];
  const float* fusion_w = (const float*)d_in[1];
  const float* fusion_b = (const float*)d_in[2];
  const float* ln_g     = (const float*)d_in[3];
  const float* ln_b     = (const float*)d_in[4];
  const float* f_in_w   = (const float*)d_in[5];
  const float* f_conv_w = (const float*)d_in[6];
  const float* f_conv_b = (const float*)d_in[7];
  const float* f_xproj  = (const float*)d_in[8];
  const float* f_dt_w   = (const float*)d_in[9];
  const float* f_dt_b   = (const float*)d_in[10];
  const float* f_A_log  = (const float*)d_in[11];
  const float* f_D      = (const float*)d_in[12];
  const float* f_out_w  = (const float*)d_in[13];
  const float* b_in_w   = (const float*)d_in[14];
  const float* b_conv_w = (const float*)d_in[15];
  const float* b_conv_b = (const float*)d_in[16];
  const float* b_xproj  = (const float*)d_in[17];
  const float* b_dt_w   = (const float*)d_in[18];
  const float* b_dt_b   = (const float*)d_in[19];
  const float* b_A_log  = (const float*)d_in[20];
  const float* b_D      = (const float*)d_in[21];
  const float* b_out_w  = (const float*)d_in[22];

  char* w = (char*)d_ws;
  auto alloc = [&](size_t bytes) -> char* {
    char* p = w;
    w += (bytes + 255) & ~(size_t)255;
    return p;
  };
  __bf16* xbf   = (__bf16*)alloc((size_t)2048 * 512 * 2);
  __bf16* wInF  = (__bf16*)alloc((size_t)2048 * 512 * 2);
  __bf16* wInB  = (__bf16*)alloc((size_t)2048 * 512 * 2);
  __bf16* xprF  = (__bf16*)alloc((size_t)64 * 1024 * 2);
  __bf16* xprB  = (__bf16*)alloc((size_t)64 * 1024 * 2);
  __bf16* wOutF = (__bf16*)alloc((size_t)512 * 1024 * 2);
  __bf16* wOutB = (__bf16*)alloc((size_t)512 * 1024 * 2);
  __bf16* wFus  = (__bf16*)alloc((size_t)512 * 1024 * 2);
  float*  xzbuf = (float*)alloc((size_t)2 * 2048 * 2048 * 4);
  float*  xi32  = (float*)alloc((size_t)2 * 2048 * 1024 * 4);
  __bf16* xi16  = (__bf16*)alloc((size_t)2 * 2048 * 1024 * 2);
  float*  xdbl  = (float*)alloc((size_t)2 * 2048 * 64 * 4);
  float*  dlt   = (float*)alloc((size_t)2 * 2048 * 1024 * 4);
  __bf16* ybf   = (__bf16*)alloc((size_t)2 * 2048 * 1024 * 2);
  __bf16* fin   = (__bf16*)alloc((size_t)2048 * 1024 * 2);
  float*  rbuf  = (float*)alloc((size_t)2048 * 512 * 4);
  (void)ws_size; (void)n_in; (void)in_sizes; (void)out_size;

  // 1) casts
  CastArgs ca;
  ca.s[0] = { x,        xbf,   (2048 * 512) / 4 };
  ca.s[1] = { f_in_w,   wInF,  (2048 * 512) / 4 };
  ca.s[2] = { b_in_w,   wInB,  (2048 * 512) / 4 };
  ca.s[3] = { f_xproj,  xprF,  (64 * 1024) / 4 };
  ca.s[4] = { b_xproj,  xprB,  (64 * 1024) / 4 };
  ca.s[5] = { f_out_w,  wOutF, (512 * 1024) / 4 };
  ca.s[6] = { b_out_w,  wOutB, (512 * 1024) / 4 };
  ca.s[7] = { fusion_w, wFus,  (512 * 1024) / 4 };
  cast_kernel<<<dim3(256, 8), 256, 0, stream>>>(ca);

  // 2) G1: xz[dir] = x @ in_w^T   (M=2048, N=2048, K=512)
  gemm_bt<float, false, false><<<dim3(16, 16, 2), 256, 0, stream>>>(
      xbf, 0LL, wInF, wInB, xzbuf, (long long)2048 * 2048, 2048, 2048, 512,
      nullptr, nullptr, 0);

  // 3) conv + SiLU -> xi (f32 + bf16)
  conv_silu_kernel<<<dim3(4, 8, 4), 256, 0, stream>>>(
      xzbuf, f_conv_w, f_conv_b, b_conv_w, b_conv_b, xi32, xi16);

  // 4) G2: x_dbl[dir] = xi @ xproj^T   (N=64, K=1024)
  gemm_bt<float, false, false><<<dim3(1, 16, 2), 256, 0, stream>>>(
      xi16, (long long)2048 * 1024, xprF, xprB, xdbl, (long long)2048 * 64, 64,
      64, 1024, nullptr, nullptr, 0);

  // 5) delta
  delta_kernel<<<dim3(4, 64, 2), 256, 0, stream>>>(
      xdbl, f_dt_w, f_dt_b, b_dt_w, b_dt_b, dlt);

  // 6) scan (+ D skip + SiLU gate) -> y bf16
  scan_kernel<<<dim3(64, 2, 2), 256, 0, stream>>>(
      dlt, xi32, xdbl, xzbuf, f_A_log, f_D, b_A_log, b_D, ybf);

  // 7) G4: fused_in[:, dir*512:+512] = y @ out_w^T  (N=512, K=1024)
  gemm_bt<__bf16, false, false><<<dim3(4, 16, 2), 256, 0, stream>>>(
      ybf, (long long)2048 * 1024, wOutF, wOutB, fin, 512LL, 1024, 512, 1024,
      nullptr, nullptr, 0);

  // 8) G5: r = x + fused_in @ fusion_w^T + fusion_b  (N=512, K=1024)
  gemm_bt<float, true, true><<<dim3(4, 16, 1), 256, 0, stream>>>(
      fin, 0LL, wFus, wFus, rbuf, 0LL, 512, 512, 1024,
      fusion_b, x, 512);

  // 9) LayerNorm -> d_out
  ln_kernel<<<2048, 256, 0, stream>>>(rbuf, ln_g, ln_b, (float*)d_out);
}

// Round 2
// 505.635 us; speedup vs baseline: 1.7536x; 1.7536x over previous
//
#include <hip/hip_runtime.h>
#include <hip/hip_bf16.h>

// ---------------- types & helpers ----------------
typedef __bf16 bf16x8 __attribute__((ext_vector_type(8)));
typedef __bf16 bf16x4 __attribute__((ext_vector_type(4)));
typedef float  f32x4  __attribute__((ext_vector_type(4)));

#define LOG2E 1.44269504088896340f

static __device__ __forceinline__ unsigned short f2bf_bits(float f) {
  unsigned u = __builtin_bit_cast(unsigned, f);
  u = u + 0x7FFFu + ((u >> 16) & 1u);   // RNE
  return (unsigned short)(u >> 16);
}
static __device__ __forceinline__ __bf16 to_bf16(float f) {
  unsigned short s = f2bf_bits(f);
  return __builtin_bit_cast(__bf16, s);
}
static __device__ __forceinline__ float fast_sigmoid(float x) {
  return __builtin_amdgcn_rcpf(1.f + __builtin_amdgcn_exp2f(-LOG2E * x));
}

// ---------------- cast f32 -> bf16 (8 segments) ----------------
struct CastSeg { const float* src; __bf16* dst; int n4; };
struct CastArgs { CastSeg s[8]; };

__global__ __launch_bounds__(256) void cast_kernel(CastArgs a) {
  CastSeg seg = a.s[blockIdx.y];
  int idx = blockIdx.x * 256 + threadIdx.x;
  int stride = gridDim.x * 256;
  const float4* src = (const float4*)seg.src;
  bf16x4* dst = (bf16x4*)seg.dst;
  for (int i = idx; i < seg.n4; i += stride) {
    float4 v = src[i];
    bf16x4 o;
    o[0] = to_bf16(v.x); o[1] = to_bf16(v.y);
    o[2] = to_bf16(v.z); o[3] = to_bf16(v.w);
    dst[i] = o;
  }
}

// ---------------- GEMM: C[M,N] = A[M,K] @ B[N,K]^T (+bias)(+resid) ----------
template<typename OutT, bool BIAS, bool RESID>
__global__ __launch_bounds__(256) void gemm_bt(
    const __bf16* __restrict__ A, long long sAz,
    const __bf16* __restrict__ B0, const __bf16* __restrict__ B1,
    OutT* __restrict__ C, long long sCz, int ldc,
    int N, int K,
    const float* __restrict__ bias, const float* __restrict__ resid, int ldr)
{
  const __bf16* B = (blockIdx.z == 0) ? B0 : B1;
  A += (size_t)blockIdx.z * (size_t)sAz;
  C += (size_t)blockIdx.z * (size_t)sCz;
  int lane = threadIdx.x & 63;
  int wid  = threadIdx.x >> 6;
  int rowBase = blockIdx.y * 128 + (wid >> 1) * 64;
  int colBase = blockIdx.x * 128 + (wid & 1) * 64;
  int lr = lane & 15;
  int lk = (lane >> 4) << 3;           // k-offset within 32-chunk
  const __bf16* Ap = A + (size_t)(rowBase + lr) * K + lk;
  const __bf16* Bp[4];
  #pragma unroll
  for (int ni = 0; ni < 4; ++ni) {
    int br = colBase + ni * 16 + lr;
    if (br > N - 1) br = N - 1;        // clamp (stores masked below)
    Bp[ni] = B + (size_t)br * K + lk;
  }
  f32x4 acc[4][4] = {};
  #pragma unroll 2
  for (int k = 0; k < K; k += 32) {
    bf16x8 aF[4], bF[4];
    #pragma unroll
    for (int mi = 0; mi < 4; ++mi)
      aF[mi] = *(const bf16x8*)(Ap + (size_t)(mi * 16) * K + k);
    #pragma unroll
    for (int ni = 0; ni < 4; ++ni)
      bF[ni] = *(const bf16x8*)(Bp[ni] + k);
    #pragma unroll
    for (int mi = 0; mi < 4; ++mi)
      #pragma unroll
      for (int ni = 0; ni < 4; ++ni)
        acc[mi][ni] = __builtin_amdgcn_mfma_f32_16x16x32_bf16(aF[mi], bF[ni], acc[mi][ni], 0, 0, 0);
  }
  int crow = rowBase + ((lane >> 4) << 2);
  int ccol = colBase + lr;
  #pragma unroll
  for (int mi = 0; mi < 4; ++mi) {
    #pragma unroll
    for (int ni = 0; ni < 4; ++ni) {
      int c = ccol + ni * 16;
      if (c < N) {
        #pragma unroll
        for (int j = 0; j < 4; ++j) {
          int r = crow + mi * 16 + j;
          float v = acc[mi][ni][j];
          if (BIAS)  v += bias[c];
          if (RESID) v += resid[(size_t)r * ldr + c];
          if constexpr (sizeof(OutT) == 2) C[(size_t)r * ldc + c] = to_bf16(v);
          else                             C[(size_t)r * ldc + c] = v;
        }
      }
    }
  }
}

// ---------------- causal depthwise conv (both directions) + SiLU ------------
__global__ __launch_bounds__(256) void conv_silu_kernel(
    const float* __restrict__ xz,     // [dir][2048][2048], xi = cols 0..1023
    const float* __restrict__ f_cw, const float* __restrict__ f_cb,
    const float* __restrict__ b_cw, const float* __restrict__ b_cb,
    float* __restrict__ xi32,         // [dir][2048][1024]
    __bf16* __restrict__ xi16)        // [dir][2048][1024]
{
  int d  = blockIdx.x * 256 + threadIdx.x;   // 0..1023
  int t0 = blockIdx.y * 128;
  int dir = blockIdx.z >> 1, b = blockIdx.z & 1;
  const float* cw = dir ? b_cw : f_cw;
  const float* cb = dir ? b_cb : f_cb;
  float w0 = cw[d*4+0], w1 = cw[d*4+1], w2 = cw[d*4+2], w3 = cw[d*4+3];
  float bias = cb[d];
  size_t rowBase = (size_t)dir * 2048 + (size_t)b * 1024;
  const float* xp = xz + rowBase * 2048 + d;
  float* o32 = xi32 + rowBase * 1024 + d;
  __bf16* o16 = xi16 + rowBase * 1024 + d;
  auto X = [&](int t) -> float {
    return (t >= 0 && t < 1024) ? xp[(size_t)t * 2048] : 0.f;
  };
  if (dir == 0) {
    float a = X(t0-3), bb = X(t0-2), c = X(t0-1);
    for (int t = t0; t < t0 + 128; ++t) {
      float cur = xp[(size_t)t * 2048];
      float v = fmaf(w0, a, fmaf(w1, bb, fmaf(w2, c, fmaf(w3, cur, bias))));
      float s = v * fast_sigmoid(v);
      o32[(size_t)t * 1024] = s;
      o16[(size_t)t * 1024] = to_bf16(s);
      a = bb; bb = c; c = cur;
    }
  } else {
    float a = X(t0), bb = X(t0+1), c = X(t0+2);
    for (int t = t0; t < t0 + 128; ++t) {
      float nx = X(t + 3);
      float v = fmaf(w3, a, fmaf(w2, bb, fmaf(w1, c, fmaf(w0, nx, bias))));
      float s = v * fast_sigmoid(v);
      o32[(size_t)t * 1024] = s;
      o16[(size_t)t * 1024] = to_bf16(s);
      a = bb; bb = c; c = nx;
    }
  }
}

// ---------------- delta = softplus(dt @ dt_w^T + dt_b) ----------------------
__global__ __launch_bounds__(256) void delta_kernel(
    const float* __restrict__ xdbl,   // [dir][2048][64], dt = cols 0..31
    const float* __restrict__ f_dtw, const float* __restrict__ f_dtb,
    const float* __restrict__ b_dtw, const float* __restrict__ b_dtb,
    float* __restrict__ delta)        // [dir][2048][1024]
{
  int d = blockIdx.x * 256 + threadIdx.x;
  int dir = blockIdx.z;
  const float* dtw = dir ? b_dtw : f_dtw;
  const float* dtb = dir ? b_dtb : f_dtb;
  float w[32];
  #pragma unroll
  for (int k = 0; k < 32; ++k) w[k] = dtw[d * 32 + k];
  float bias = dtb[d];
  int row0 = blockIdx.y * 32;
  size_t base = (size_t)dir * 2048;
  for (int r = 0; r < 32; ++r) {
    int row = row0 + r;
    const float4* xr = (const float4*)(xdbl + (base + row) * 64);
    float acc = bias;
    #pragma unroll
    for (int q = 0; q < 8; ++q) {
      float4 v = xr[q];
      acc = fmaf(w[q*4+0], v.x, acc);
      acc = fmaf(w[q*4+1], v.y, acc);
      acc = fmaf(w[q*4+2], v.z, acc);
      acc = fmaf(w[q*4+3], v.w, acc);
    }
    float m = fmaxf(acc, 0.f);
    float e = __builtin_amdgcn_exp2f(-LOG2E * fabsf(acc));
    float sp = fmaf(__builtin_amdgcn_logf(1.f + e), 1.f / LOG2E, m);
    delta[(base + row) * 1024 + d] = sp;
  }
}

// ---------------- chunked parallel scan ------------------------------------
// h_t = a_t h_{t-1} + b_t  with a_t = exp2(delta*As), b_t = delta*B*xi.
// NC=16 chunks x CL=64 steps. lane = (channel c = tid>>4, state n = tid&15).
#define NC 16
#define CL 64

// pass1: per chunk, from h=0: aProd = prod(a), hPart = partial state.
__global__ __launch_bounds__(256) void scan_part1(
    const float* __restrict__ delta,  // [dir][2048][1024]
    const float* __restrict__ xi32,   // [dir][2048][1024]
    const float* __restrict__ xdbl,   // [dir][2048][64]  (B: 32+n)
    const float* __restrict__ f_Alog, const float* __restrict__ b_Alog,
    float* __restrict__ aProd,        // [zb][NC][1024][16]
    float* __restrict__ hPart)        // [zb][NC][1024][16]
{
  int n = threadIdx.x & 15;
  int c = threadIdx.x >> 4;
  int d = blockIdx.x * 16 + c;
  int g = blockIdx.y;               // chunk
  int zb = blockIdx.z;              // dir*2 + b
  int dir = zb >> 1, b = zb & 1;
  const float* Alog = dir ? b_Alog : f_Alog;
  float As = -__builtin_amdgcn_exp2f(LOG2E * Alog[d * 16 + n]) * LOG2E;
  size_t base = (size_t)dir * 2048 + (size_t)b * 1024;
  auto rowOf = [&](int tau) -> size_t {
    int t = dir ? (1023 - tau) : tau;
    return base + (size_t)t;
  };
  int t0 = g * CL;
  constexpr int PF = 8;
  float pdel[PF], pxi[PF], pB[PF];
  #pragma unroll
  for (int j = 0; j < PF; ++j) {
    size_t row = rowOf(t0 + j);
    pdel[j] = delta[row * 1024 + d];
    pxi[j]  = xi32[row * 1024 + d];
    pB[j]   = xdbl[row * 64 + 32 + n];
  }
  float A = 1.f, H = 0.f;
  for (int tb = 0; tb < CL; tb += PF) {
    #pragma unroll
    for (int j = 0; j < PF; ++j) {
      float del = pdel[j], xv = pxi[j], Bv = pB[j];
      int tn = tb + j + PF;
      if (tn < CL) {
        size_t rn = rowOf(t0 + tn);
        pdel[j] = delta[rn * 1024 + d];
        pxi[j]  = xi32[rn * 1024 + d];
        pB[j]   = xdbl[rn * 64 + 32 + n];
      }
      float a = __builtin_amdgcn_exp2f(del * As);
      H = fmaf(a, H, del * Bv * xv);
      A *= a;
    }
  }
  size_t o = ((size_t)zb * NC + g) * 16384 + (size_t)d * 16 + n;
  aProd[o] = A;
  hPart[o] = H;
}

// pass2: per (zb, d, n): serial over NC chunks -> incoming state per chunk.
__global__ __launch_bounds__(256) void scan_combine(
    const float* __restrict__ aProd, const float* __restrict__ hPart,
    float* __restrict__ hIn)
{
  int idx = blockIdx.x * 256 + threadIdx.x;   // 0..65535
  int zb = idx >> 14;
  int dn = idx & 16383;
  float a[NC], hp[NC];
  #pragma unroll
  for (int g = 0; g < NC; ++g) {
    size_t o = ((size_t)zb * NC + g) * 16384 + dn;
    a[g] = aProd[o];
    hp[g] = hPart[o];
  }
  float H = 0.f;
  #pragma unroll
  for (int g = 0; g < NC; ++g) {
    size_t o = ((size_t)zb * NC + g) * 16384 + dn;
    hIn[o] = H;
    H = fmaf(a[g], H, hp[g]);
  }
}

// pass3: re-scan chunk from hIn, C-dot via swizzle, D-skip, SiLU(z) gate.
__global__ __launch_bounds__(256) void scan_part3(
    const float* __restrict__ delta,
    const float* __restrict__ xi32,
    const float* __restrict__ xdbl,   // (B: 32+n, C: 48+n)
    const float* __restrict__ xz,     // z at col 1024+d
    const float* __restrict__ f_Alog, const float* __restrict__ f_D,
    const float* __restrict__ b_Alog, const float* __restrict__ b_D,
    const float* __restrict__ hIn,
    __bf16* __restrict__ yout)        // [dir][2048][1024]
{
  int n = threadIdx.x & 15;
  int c = threadIdx.x >> 4;
  int d = blockIdx.x * 16 + c;
  int g = blockIdx.y;
  int zb = blockIdx.z;
  int dir = zb >> 1, b = zb & 1;
  const float* Alog = dir ? b_Alog : f_Alog;
  const float* Dp   = dir ? b_D   : f_D;
  float As = -__builtin_amdgcn_exp2f(LOG2E * Alog[d * 16 + n]) * LOG2E;
  float Dv = Dp[d];
  size_t base = (size_t)dir * 2048 + (size_t)b * 1024;
  auto rowOf = [&](int tau) -> size_t {
    int t = dir ? (1023 - tau) : tau;
    return base + (size_t)t;
  };
  int t0 = g * CL;
  constexpr int PF = 8;
  float pdel[PF], pxi[PF], pB[PF], pC[PF], pz[PF];
  #pragma unroll
  for (int j = 0; j < PF; ++j) {
    size_t row = rowOf(t0 + j);
    pdel[j] = delta[row * 1024 + d];
    pxi[j]  = xi32[row * 1024 + d];
    pB[j]   = xdbl[row * 64 + 32 + n];
    pC[j]   = xdbl[row * 64 + 48 + n];
    pz[j]   = xz[row * 2048 + 1024 + d];
  }
  float h = hIn[((size_t)zb * NC + g) * 16384 + (size_t)d * 16 + n];
  for (int tb = 0; tb < CL; tb += PF) {
    #pragma unroll
    for (int j = 0; j < PF; ++j) {
      int tau = t0 + tb + j;
      size_t row = rowOf(tau);
      float del = pdel[j], xv = pxi[j], Bv = pB[j], Cv = pC[j], zz = pz[j];
      int tn = tb + j + PF;
      if (tn < CL) {
        size_t rn = rowOf(t0 + tn);
        pdel[j] = delta[rn * 1024 + d];
        pxi[j]  = xi32[rn * 1024 + d];
        pB[j]   = xdbl[rn * 64 + 32 + n];
        pC[j]   = xdbl[rn * 64 + 48 + n];
        pz[j]   = xz[rn * 2048 + 1024 + d];
      }
      float dA = __builtin_amdgcn_exp2f(del * As);
      h = fmaf(dA, h, del * Bv * xv);
      float p = h * Cv;
      p += __builtin_bit_cast(float, __builtin_amdgcn_ds_swizzle(__builtin_bit_cast(int, p), 0x041F));
      p += __builtin_bit_cast(float, __builtin_amdgcn_ds_swizzle(__builtin_bit_cast(int, p), 0x081F));
      p += __builtin_bit_cast(float, __builtin_amdgcn_ds_swizzle(__builtin_bit_cast(int, p), 0x101F));
      p += __builtin_bit_cast(float, __builtin_amdgcn_ds_swizzle(__builtin_bit_cast(int, p), 0x201F));
      float yv = (p + xv * Dv) * (zz * fast_sigmoid(zz));
      if (n == 0) yout[row * 1024 + d] = to_bf16(yv);
    }
  }
}

// ---------------- LayerNorm over last dim (512) -----------------------------
__global__ __launch_bounds__(256) void ln_kernel(
    const float* __restrict__ r, const float* __restrict__ g,
    const float* __restrict__ beta, float* __restrict__ out)
{
  int row = blockIdx.x;
  int tid = threadIdx.x;
  const float* rp = r + (size_t)row * 512;
  float v0 = rp[tid], v1 = rp[tid + 256];
  float s = v0 + v1;
  float q = fmaf(v0, v0, v1 * v1);
  #pragma unroll
  for (int m = 1; m < 64; m <<= 1) {
    s += __shfl_xor(s, m, 64);
    q += __shfl_xor(q, m, 64);
  }
  __shared__ float ls[4], lq[4];
  int wid = tid >> 6;
  if ((tid & 63) == 0) { ls[wid] = s; lq[wid] = q; }
  __syncthreads();
  s = ls[0] + ls[1] + ls[2] + ls[3];
  q = lq[0] + lq[1] + lq[2] + lq[3];
  float mu = s * (1.f / 512.f);
  float var = q * (1.f / 512.f) - mu * mu;
  float rs = rsqrtf(var + 1e-5f);
  float* op = out + (size_t)row * 512;
  op[tid]       = (v0 - mu) * rs * g[tid]       + beta[tid];
  op[tid + 256] = (v1 - mu) * rs * g[tid + 256] + beta[tid + 256];
}

// ---------------- host launch ----------------
extern "C" void kernel_launch(void* const* d_in, const int* in_sizes, int n_in,
                              void* d_out, int out_size, void* d_ws, size_t ws_size,
                              hipStream_t stream)
{
  const float* x        = (const float*)d_in[0];
  const float* fusion_w = (const float*)d_in[1];
  const float* fusion_b = (const float*)d_in[2];
  const float* ln_g     = (const float*)d_in[3];
  const float* ln_b     = (const float*)d_in[4];
  const float* f_in_w   = (const float*)d_in[5];
  const float* f_conv_w = (const float*)d_in[6];
  const float* f_conv_b = (const float*)d_in[7];
  const float* f_xproj  = (const float*)d_in[8];
  const float* f_dt_w   = (const float*)d_in[9];
  const float* f_dt_b   = (const float*)d_in[10];
  const float* f_A_log  = (const float*)d_in[11];
  const float* f_D      = (const float*)d_in[12];
  const float* f_out_w  = (const float*)d_in[13];
  const float* b_in_w   = (const float*)d_in[14];
  const float* b_conv_w = (const float*)d_in[15];
  const float* b_conv_b = (const float*)d_in[16];
  const float* b_xproj  = (const float*)d_in[17];
  const float* b_dt_w   = (const float*)d_in[18];
  const float* b_dt_b   = (const float*)d_in[19];
  const float* b_A_log  = (const float*)d_in[20];
  const float* b_D      = (const float*)d_in[21];
  const float* b_out_w  = (const float*)d_in[22];

  char* w = (char*)d_ws;
  auto alloc = [&](size_t bytes) -> char* {
    char* p = w;
    w += (bytes + 255) & ~(size_t)255;
    return p;
  };
  __bf16* xbf   = (__bf16*)alloc((size_t)2048 * 512 * 2);
  __bf16* wInF  = (__bf16*)alloc((size_t)2048 * 512 * 2);
  __bf16* wInB  = (__bf16*)alloc((size_t)2048 * 512 * 2);
  __bf16* xprF  = (__bf16*)alloc((size_t)64 * 1024 * 2);
  __bf16* xprB  = (__bf16*)alloc((size_t)64 * 1024 * 2);
  __bf16* wOutF = (__bf16*)alloc((size_t)512 * 1024 * 2);
  __bf16* wOutB = (__bf16*)alloc((size_t)512 * 1024 * 2);
  __bf16* wFus  = (__bf16*)alloc((size_t)512 * 1024 * 2);
  float*  xzbuf = (float*)alloc((size_t)2 * 2048 * 2048 * 4);
  float*  xi32  = (float*)alloc((size_t)2 * 2048 * 1024 * 4);
  __bf16* xi16  = (__bf16*)alloc((size_t)2 * 2048 * 1024 * 2);
  float*  xdbl  = (float*)alloc((size_t)2 * 2048 * 64 * 4);
  float*  dlt   = (float*)alloc((size_t)2 * 2048 * 1024 * 4);
  __bf16* ybf   = (__bf16*)alloc((size_t)2 * 2048 * 1024 * 2);
  __bf16* fin   = (__bf16*)alloc((size_t)2048 * 1024 * 2);
  float*  rbuf  = (float*)alloc((size_t)2048 * 512 * 4);
  float*  aProd = (float*)alloc((size_t)4 * NC * 16384 * 4);
  float*  hPart = (float*)alloc((size_t)4 * NC * 16384 * 4);
  float*  hInB  = (float*)alloc((size_t)4 * NC * 16384 * 4);
  (void)ws_size; (void)n_in; (void)in_sizes; (void)out_size;

  // 1) casts
  CastArgs ca;
  ca.s[0] = { x,        xbf,   (2048 * 512) / 4 };
  ca.s[1] = { f_in_w,   wInF,  (2048 * 512) / 4 };
  ca.s[2] = { b_in_w,   wInB,  (2048 * 512) / 4 };
  ca.s[3] = { f_xproj,  xprF,  (64 * 1024) / 4 };
  ca.s[4] = { b_xproj,  xprB,  (64 * 1024) / 4 };
  ca.s[5] = { f_out_w,  wOutF, (512 * 1024) / 4 };
  ca.s[6] = { b_out_w,  wOutB, (512 * 1024) / 4 };
  ca.s[7] = { fusion_w, wFus,  (512 * 1024) / 4 };
  cast_kernel<<<dim3(256, 8), 256, 0, stream>>>(ca);

  // 2) G1: xz[dir] = x @ in_w^T   (M=2048, N=2048, K=512)
  gemm_bt<float, false, false><<<dim3(16, 16, 2), 256, 0, stream>>>(
      xbf, 0LL, wInF, wInB, xzbuf, (long long)2048 * 2048, 2048, 2048, 512,
      nullptr, nullptr, 0);

  // 3) conv + SiLU -> xi (f32 + bf16)
  conv_silu_kernel<<<dim3(4, 8, 4), 256, 0, stream>>>(
      xzbuf, f_conv_w, f_conv_b, b_conv_w, b_conv_b, xi32, xi16);

  // 4) G2: x_dbl[dir] = xi @ xproj^T   (N=64, K=1024)
  gemm_bt<float, false, false><<<dim3(1, 16, 2), 256, 0, stream>>>(
      xi16, (long long)2048 * 1024, xprF, xprB, xdbl, (long long)2048 * 64, 64,
      64, 1024, nullptr, nullptr, 0);

  // 5) delta
  delta_kernel<<<dim3(4, 64, 2), 256, 0, stream>>>(
      xdbl, f_dt_w, f_dt_b, b_dt_w, b_dt_b, dlt);

  // 6) chunked scan: pass1 -> combine -> pass3
  scan_part1<<<dim3(64, NC, 4), 256, 0, stream>>>(
      dlt, xi32, xdbl, f_A_log, b_A_log, aProd, hPart);
  scan_combine<<<dim3(256), 256, 0, stream>>>(aProd, hPart, hInB);
  scan_part3<<<dim3(64, NC, 4), 256, 0, stream>>>(
      dlt, xi32, xdbl, xzbuf, f_A_log, f_D, b_A_log, b_D, hInB, ybf);

  // 7) G4: fused_in[:, dir*512:+512] = y @ out_w^T  (N=512, K=1024)
  gemm_bt<__bf16, false, false><<<dim3(4, 16, 2), 256, 0, stream>>>(
      ybf, (long long)2048 * 1024, wOutF, wOutB, fin, 512LL, 1024, 512, 1024,
      nullptr, nullptr, 0);

  // 8) G5: r = x + fused_in @ fusion_w^T + fusion_b  (N=512, K=1024)
  gemm_bt<float, true, true><<<dim3(4, 16, 1), 256, 0, stream>>>(
      fin, 0LL, wFus, wFus, rbuf, 0LL, 512, 512, 1024,
      fusion_b, x, 512);

  // 9) LayerNorm -> d_out
  ln_kernel<<<2048, 256, 0, stream>>>(rbuf, ln_g, ln_b, (float*)d_out);
}

// Round 3
// 456.029 us; speedup vs baseline: 1.9444x; 1.1088x over previous
//
#include <hip/hip_runtime.h>
#include <hip/hip_bf16.h>

// ---------------- types & helpers ----------------
typedef __bf16 bf16x8 __attribute__((ext_vector_type(8)));
typedef __bf16 bf16x4 __attribute__((ext_vector_type(4)));
typedef float  f32x4  __attribute__((ext_vector_type(4)));

#define LOG2E 1.44269504088896340f

static __device__ __forceinline__ unsigned short f2bf_bits(float f) {
  unsigned u = __builtin_bit_cast(unsigned, f);
  u = u + 0x7FFFu + ((u >> 16) & 1u);   // RNE
  return (unsigned short)(u >> 16);
}
static __device__ __forceinline__ __bf16 to_bf16(float f) {
  unsigned short s = f2bf_bits(f);
  return __builtin_bit_cast(__bf16, s);
}
static __device__ __forceinline__ float fast_sigmoid(float x) {
  return __builtin_amdgcn_rcpf(1.f + __builtin_amdgcn_exp2f(-LOG2E * x));
}
// DPP rotate-add within 16-lane rows: p += rot(p, k). CTRL = 0x120|k (ROW_ROR).
template<int CTRL>
static __device__ __forceinline__ float dpp_rot_add(float p) {
  int v = __builtin_amdgcn_update_dpp(0, __builtin_bit_cast(int, p), CTRL, 0xF, 0xF, false);
  return p + __builtin_bit_cast(float, v);
}

// ---------------- cast f32 -> bf16 (8 segments) ----------------
struct CastSeg { const float* src; __bf16* dst; int n4; };
struct CastArgs { CastSeg s[8]; };

__global__ __launch_bounds__(256) void cast_kernel(CastArgs a) {
  CastSeg seg = a.s[blockIdx.y];
  int idx = blockIdx.x * 256 + threadIdx.x;
  int stride = gridDim.x * 256;
  const float4* src = (const float4*)seg.src;
  bf16x4* dst = (bf16x4*)seg.dst;
  for (int i = idx; i < seg.n4; i += stride) {
    float4 v = src[i];
    bf16x4 o;
    o[0] = to_bf16(v.x); o[1] = to_bf16(v.y);
    o[2] = to_bf16(v.z); o[3] = to_bf16(v.w);
    dst[i] = o;
  }
}

// ---------------- GEMM: C[M,N] = A[M,K] @ B[N,K]^T (+bias)(+resid) ----------
template<typename OutT, bool BIAS, bool RESID>
__global__ __launch_bounds__(256) void gemm_bt(
    const __bf16* __restrict__ A, long long sAz,
    const __bf16* __restrict__ B0, const __bf16* __restrict__ B1,
    OutT* __restrict__ C, long long sCz, int ldc,
    int N, int K,
    const float* __restrict__ bias, const float* __restrict__ resid, int ldr)
{
  const __bf16* B = (blockIdx.z == 0) ? B0 : B1;
  A += (size_t)blockIdx.z * (size_t)sAz;
  C += (size_t)blockIdx.z * (size_t)sCz;
  int lane = threadIdx.x & 63;
  int wid  = threadIdx.x >> 6;
  int rowBase = blockIdx.y * 128 + (wid >> 1) * 64;
  int colBase = blockIdx.x * 128 + (wid & 1) * 64;
  int lr = lane & 15;
  int lk = (lane >> 4) << 3;           // k-offset within 32-chunk
  const __bf16* Ap = A + (size_t)(rowBase + lr) * K + lk;
  const __bf16* Bp[4];
  #pragma unroll
  for (int ni = 0; ni < 4; ++ni) {
    int br = colBase + ni * 16 + lr;
    if (br > N - 1) br = N - 1;        // clamp (stores masked below)
    Bp[ni] = B + (size_t)br * K + lk;
  }
  f32x4 acc[4][4] = {};
  #pragma unroll 2
  for (int k = 0; k < K; k += 32) {
    bf16x8 aF[4], bF[4];
    #pragma unroll
    for (int mi = 0; mi < 4; ++mi)
      aF[mi] = *(const bf16x8*)(Ap + (size_t)(mi * 16) * K + k);
    #pragma unroll
    for (int ni = 0; ni < 4; ++ni)
      bF[ni] = *(const bf16x8*)(Bp[ni] + k);
    #pragma unroll
    for (int mi = 0; mi < 4; ++mi)
      #pragma unroll
      for (int ni = 0; ni < 4; ++ni)
        acc[mi][ni] = __builtin_amdgcn_mfma_f32_16x16x32_bf16(aF[mi], bF[ni], acc[mi][ni], 0, 0, 0);
  }
  int crow = rowBase + ((lane >> 4) << 2);
  int ccol = colBase + lr;
  #pragma unroll
  for (int mi = 0; mi < 4; ++mi) {
    #pragma unroll
    for (int ni = 0; ni < 4; ++ni) {
      int c = ccol + ni * 16;
      if (c < N) {
        #pragma unroll
        for (int j = 0; j < 4; ++j) {
          int r = crow + mi * 16 + j;
          float v = acc[mi][ni][j];
          if (BIAS)  v += bias[c];
          if (RESID) v += resid[(size_t)r * ldr + c];
          if constexpr (sizeof(OutT) == 2) C[(size_t)r * ldc + c] = to_bf16(v);
          else                             C[(size_t)r * ldc + c] = v;
        }
      }
    }
  }
}

// ---------------- causal depthwise conv (both directions) + SiLU ------------
__global__ __launch_bounds__(256) void conv_silu_kernel(
    const float* __restrict__ xz,     // [dir][2048][2048], xi = cols 0..1023
    const float* __restrict__ f_cw, const float* __restrict__ f_cb,
    const float* __restrict__ b_cw, const float* __restrict__ b_cb,
    float* __restrict__ xi32,         // [dir][2048][1024]
    __bf16* __restrict__ xi16)        // [dir][2048][1024]
{
  int d  = blockIdx.x * 256 + threadIdx.x;   // 0..1023
  int t0 = blockIdx.y * 128;
  int dir = blockIdx.z >> 1, b = blockIdx.z & 1;
  const float* cw = dir ? b_cw : f_cw;
  const float* cb = dir ? b_cb : f_cb;
  float w0 = cw[d*4+0], w1 = cw[d*4+1], w2 = cw[d*4+2], w3 = cw[d*4+3];
  float bias = cb[d];
  size_t rowBase = (size_t)dir * 2048 + (size_t)b * 1024;
  const float* xp = xz + rowBase * 2048 + d;
  float* o32 = xi32 + rowBase * 1024 + d;
  __bf16* o16 = xi16 + rowBase * 1024 + d;
  auto X = [&](int t) -> float {
    return (t >= 0 && t < 1024) ? xp[(size_t)t * 2048] : 0.f;
  };
  if (dir == 0) {
    float a = X(t0-3), bb = X(t0-2), c = X(t0-1);
    for (int t = t0; t < t0 + 128; ++t) {
      float cur = xp[(size_t)t * 2048];
      float v = fmaf(w0, a, fmaf(w1, bb, fmaf(w2, c, fmaf(w3, cur, bias))));
      float s = v * fast_sigmoid(v);
      o32[(size_t)t * 1024] = s;
      o16[(size_t)t * 1024] = to_bf16(s);
      a = bb; bb = c; c = cur;
    }
  } else {
    float a = X(t0), bb = X(t0+1), c = X(t0+2);
    for (int t = t0; t < t0 + 128; ++t) {
      float nx = X(t + 3);
      float v = fmaf(w3, a, fmaf(w2, bb, fmaf(w1, c, fmaf(w0, nx, bias))));
      float s = v * fast_sigmoid(v);
      o32[(size_t)t * 1024] = s;
      o16[(size_t)t * 1024] = to_bf16(s);
      a = bb; bb = c; c = nx;
    }
  }
}

// ---------------- prep: delta + {del, del*xi} pack + in-place silu(z) -------
__global__ __launch_bounds__(256) void prep_kernel(
    float* __restrict__ xz,           // [dir][2048][2048]; cols 1024+ -> gate (in place)
    const float* __restrict__ xi32,   // [dir][2048][1024]
    const float* __restrict__ xdbl,   // [dir][2048][64], dt = cols 0..31
    const float* __restrict__ f_dtw, const float* __restrict__ f_dtb,
    const float* __restrict__ b_dtw, const float* __restrict__ b_dtb,
    float2* __restrict__ pack2)       // [dir][2048][1024] = {delta, delta*xi}
{
  int d = blockIdx.x * 256 + threadIdx.x;
  int dir = blockIdx.z;
  const float* dtw = dir ? b_dtw : f_dtw;
  const float* dtb = dir ? b_dtb : f_dtb;
  float w[32];
  #pragma unroll
  for (int k = 0; k < 32; ++k) w[k] = dtw[d * 32 + k];
  float bias = dtb[d];
  int row0 = dir * 2048 + blockIdx.y * 32;
  for (int r = 0; r < 32; ++r) {
    int row = row0 + r;
    const float4* xr = (const float4*)(xdbl + (size_t)row * 64);
    float acc = bias;
    #pragma unroll
    for (int q = 0; q < 8; ++q) {
      float4 v = xr[q];
      acc = fmaf(w[q*4+0], v.x, acc);
      acc = fmaf(w[q*4+1], v.y, acc);
      acc = fmaf(w[q*4+2], v.z, acc);
      acc = fmaf(w[q*4+3], v.w, acc);
    }
    float m = fmaxf(acc, 0.f);
    float e = __builtin_amdgcn_exp2f(-LOG2E * fabsf(acc));
    float del = fmaf(__builtin_amdgcn_logf(1.f + e), 1.f / LOG2E, m);
    float xi = xi32[(size_t)row * 1024 + d];
    pack2[(size_t)row * 1024 + d] = float2{del, del * xi};
    float zz = xz[(size_t)row * 2048 + 1024 + d];
    xz[(size_t)row * 2048 + 1024 + d] = zz * fast_sigmoid(zz);
  }
}

// ---------------- BC pack: {B,C} contiguous per (row, n) --------------------
__global__ __launch_bounds__(256) void bcpack_kernel(
    const float* __restrict__ xdbl,   // [4096][64]
    float2* __restrict__ bc)          // [4096][16]
{
  int idx = blockIdx.x * 256 + threadIdx.x;  // 0..65535
  int row = idx >> 4, n = idx & 15;
  const float* src = xdbl + (size_t)row * 64;
  bc[idx] = float2{src[32 + n], src[48 + n]};
}

// ---------------- chunked parallel scan ------------------------------------
// h_t = a_t h_{t-1} + b_t, a_t = exp2(delta*As), b_t = (delta*xi)*B.
#define NC 32
#define CL 32

// pass1: per chunk from h=0: aProd = prod(a), hPart = partial state.
__global__ __launch_bounds__(256) void scan_part1(
    const float2* __restrict__ pack2, // [dir][2048][1024] {del, dx}
    const float2* __restrict__ bc,    // [4096][16] {B, C}
    const float* __restrict__ f_Alog, const float* __restrict__ b_Alog,
    float* __restrict__ aProd, float* __restrict__ hPart)  // [zb][NC][16384]
{
  int n = threadIdx.x & 15;
  int c = threadIdx.x >> 4;
  int d = blockIdx.x * 16 + c;
  int g = blockIdx.y;
  int zb = blockIdx.z;
  int dir = zb >> 1, b = zb & 1;
  const float* Alog = dir ? b_Alog : f_Alog;
  float As = -__builtin_amdgcn_exp2f(LOG2E * Alog[d * 16 + n]) * LOG2E;
  int base = dir * 2048 + b * 1024;
  int rowIdx = base + (dir ? (1023 - g * CL) : (g * CL));
  int rs = dir ? -1 : 1;
  int pIdx = rowIdx * 1024 + d, pS = rs * 1024;
  int qIdx = rowIdx * 16 + n,  qS = rs * 16;
  const float* bcf = (const float*)bc;   // B at float index 2*(row*16+n)

  float2 bp[3][4]; float bb[3][4];
  auto LOADG = [&](int bi, int gg) {
    #pragma unroll
    for (int j = 0; j < 4; ++j) {
      int t = gg * 4 + j;
      bp[bi][j] = pack2[pIdx + t * pS];
      bb[bi][j] = bcf[2 * (qIdx + t * qS)];
    }
  };
  LOADG(0, 0); LOADG(1, 1);
  float A = 1.f, H = 0.f;
  #pragma unroll
  for (int gg = 0; gg < CL / 4; ++gg) {
    if (gg + 2 < CL / 4) LOADG((gg + 2) % 3, gg + 2);
    #pragma unroll
    for (int j = 0; j < 4; ++j) {
      float2 v = bp[gg % 3][j];
      float Bv = bb[gg % 3][j];
      float dA = __builtin_amdgcn_exp2f(v.x * As);
      H = fmaf(dA, H, v.y * Bv);
      A *= dA;
    }
  }
  size_t o = ((size_t)zb * NC + g) * 16384 + (size_t)d * 16 + n;
  aProd[o] = A;
  hPart[o] = H;
}

// pass2: per (zb, d, n): serial over NC chunks -> incoming state per chunk.
__global__ __launch_bounds__(256) void scan_combine(
    const float* __restrict__ aProd, const float* __restrict__ hPart,
    float* __restrict__ hIn)
{
  int idx = blockIdx.x * 256 + threadIdx.x;   // 0..65535
  int zb = idx >> 14;
  int dn = idx & 16383;
  float a[NC], hp[NC];
  #pragma unroll
  for (int g = 0; g < NC; ++g) {
    size_t o = ((size_t)zb * NC + g) * 16384 + dn;
    a[g] = aProd[o];
    hp[g] = hPart[o];
  }
  float H = 0.f;
  #pragma unroll
  for (int g = 0; g < NC; ++g) {
    size_t o = ((size_t)zb * NC + g) * 16384 + dn;
    hIn[o] = H;
    H = fmaf(a[g], H, hp[g]);
  }
}

// pass3: re-scan chunk from hIn; C-dot via DPP rotate-add; y = (p+xi*D)*gate.
__global__ __launch_bounds__(256) void scan_part3(
    const float2* __restrict__ pack2, const float2* __restrict__ bc,
    const float* __restrict__ xi32,
    const float* __restrict__ gatebuf, // = xz, gate at col 1024+d
    const float* __restrict__ f_Alog, const float* __restrict__ f_D,
    const float* __restrict__ b_Alog, const float* __restrict__ b_D,
    const float* __restrict__ hIn,
    __bf16* __restrict__ yout)        // [dir][2048][1024]
{
  int n = threadIdx.x & 15;
  int c = threadIdx.x >> 4;
  int d = blockIdx.x * 16 + c;
  int g = blockIdx.y;
  int zb = blockIdx.z;
  int dir = zb >> 1, b = zb & 1;
  const float* Alog = dir ? b_Alog : f_Alog;
  float As = -__builtin_amdgcn_exp2f(LOG2E * Alog[d * 16 + n]) * LOG2E;
  float Dv = (dir ? b_D : f_D)[d];
  int base = dir * 2048 + b * 1024;
  int rowIdx = base + (dir ? (1023 - g * CL) : (g * CL));
  int rs = dir ? -1 : 1;
  int pIdx = rowIdx * 1024 + d, pS = rs * 1024;
  int qIdx = rowIdx * 16 + n,  qS = rs * 16;
  int gIdx = rowIdx * 2048 + 1024 + d, gS = rs * 2048;

  float2 bp[3][4]; float2 bbc[3][4]; float bxi[3][4]; float bgt[3][4];
  auto LOADG = [&](int bi, int gg) {
    #pragma unroll
    for (int j = 0; j < 4; ++j) {
      int t = gg * 4 + j;
      bp[bi][j]  = pack2[pIdx + t * pS];
      bbc[bi][j] = bc[qIdx + t * qS];
      bxi[bi][j] = xi32[pIdx + t * pS];
      bgt[bi][j] = gatebuf[gIdx + t * gS];
    }
  };
  LOADG(0, 0); LOADG(1, 1);
  float h = hIn[((size_t)zb * NC + g) * 16384 + (size_t)d * 16 + n];
  #pragma unroll
  for (int gg = 0; gg < CL / 4; ++gg) {
    if (gg + 2 < CL / 4) LOADG((gg + 2) % 3, gg + 2);
    #pragma unroll
    for (int j = 0; j < 4; ++j) {
      int t = gg * 4 + j;
      float2 v = bp[gg % 3][j];
      float2 w = bbc[gg % 3][j];
      float dA = __builtin_amdgcn_exp2f(v.x * As);
      h = fmaf(dA, h, v.y * w.x);
      float p = h * w.y;
      p = dpp_rot_add<0x121>(p);   // row_ror:1
      p = dpp_rot_add<0x122>(p);   // row_ror:2
      p = dpp_rot_add<0x124>(p);   // row_ror:4
      p = dpp_rot_add<0x128>(p);   // row_ror:8
      if (n == 0) {
        float yv = fmaf(bxi[gg % 3][j], Dv, p) * bgt[gg % 3][j];
        yout[pIdx + t * pS] = to_bf16(yv);
      }
    }
  }
}

// ---------------- LayerNorm over last dim (512) -----------------------------
__global__ __launch_bounds__(256) void ln_kernel(
    const float* __restrict__ r, const float* __restrict__ g,
    const float* __restrict__ beta, float* __restrict__ out)
{
  int row = blockIdx.x;
  int tid = threadIdx.x;
  const float* rp = r + (size_t)row * 512;
  float v0 = rp[tid], v1 = rp[tid + 256];
  float s = v0 + v1;
  float q = fmaf(v0, v0, v1 * v1);
  #pragma unroll
  for (int m = 1; m < 64; m <<= 1) {
    s += __shfl_xor(s, m, 64);
    q += __shfl_xor(q, m, 64);
  }
  __shared__ float ls[4], lq[4];
  int wid = tid >> 6;
  if ((tid & 63) == 0) { ls[wid] = s; lq[wid] = q; }
  __syncthreads();
  s = ls[0] + ls[1] + ls[2] + ls[3];
  q = lq[0] + lq[1] + lq[2] + lq[3];
  float mu = s * (1.f / 512.f);
  float var = q * (1.f / 512.f) - mu * mu;
  float rs = rsqrtf(var + 1e-5f);
  float* op = out + (size_t)row * 512;
  op[tid]       = (v0 - mu) * rs * g[tid]       + beta[tid];
  op[tid + 256] = (v1 - mu) * rs * g[tid + 256] + beta[tid + 256];
}

// ---------------- host launch ----------------
extern "C" void kernel_launch(void* const* d_in, const int* in_sizes, int n_in,
                              void* d_out, int out_size, void* d_ws, size_t ws_size,
                              hipStream_t stream)
{
  const float* x        = (const float*)d_in[0];
  const float* fusion_w = (const float*)d_in[1];
  const float* fusion_b = (const float*)d_in[2];
  const float* ln_g     = (const float*)d_in[3];
  const float* ln_b     = (const float*)d_in[4];
  const float* f_in_w   = (const float*)d_in[5];
  const float* f_conv_w = (const float*)d_in[6];
  const float* f_conv_b = (const float*)d_in[7];
  const float* f_xproj  = (const float*)d_in[8];
  const float* f_dt_w   = (const float*)d_in[9];
  const float* f_dt_b   = (const float*)d_in[10];
  const float* f_A_log  = (const float*)d_in[11];
  const float* f_D      = (const float*)d_in[12];
  const float* f_out_w  = (const float*)d_in[13];
  const float* b_in_w   = (const float*)d_in[14];
  const float* b_conv_w = (const float*)d_in[15];
  const float* b_conv_b = (const float*)d_in[16];
  const float* b_xproj  = (const float*)d_in[17];
  const float* b_dt_w   = (const float*)d_in[18];
  const float* b_dt_b   = (const float*)d_in[19];
  const float* b_A_log  = (const float*)d_in[20];
  const float* b_D      = (const float*)d_in[21];
  const float* b_out_w  = (const float*)d_in[22];

  char* w = (char*)d_ws;
  auto alloc = [&](size_t bytes) -> char* {
    char* p = w;
    w += (bytes + 255) & ~(size_t)255;
    return p;
  };
  __bf16* xbf   = (__bf16*)alloc((size_t)2048 * 512 * 2);
  __bf16* wInF  = (__bf16*)alloc((size_t)2048 * 512 * 2);
  __bf16* wInB  = (__bf16*)alloc((size_t)2048 * 512 * 2);
  __bf16* xprF  = (__bf16*)alloc((size_t)64 * 1024 * 2);
  __bf16* xprB  = (__bf16*)alloc((size_t)64 * 1024 * 2);
  __bf16* wOutF = (__bf16*)alloc((size_t)512 * 1024 * 2);
  __bf16* wOutB = (__bf16*)alloc((size_t)512 * 1024 * 2);
  __bf16* wFus  = (__bf16*)alloc((size_t)512 * 1024 * 2);
  float*  xzbuf = (float*)alloc((size_t)2 * 2048 * 2048 * 4);
  float*  xi32  = (float*)alloc((size_t)2 * 2048 * 1024 * 4);
  __bf16* xi16  = (__bf16*)alloc((size_t)2 * 2048 * 1024 * 2);
  float*  xdbl  = (float*)alloc((size_t)2 * 2048 * 64 * 4);
  float2* pack2 = (float2*)alloc((size_t)2 * 2048 * 1024 * 8);
  float2* bcbuf = (float2*)alloc((size_t)4096 * 16 * 8);
  __bf16* ybf   = (__bf16*)alloc((size_t)2 * 2048 * 1024 * 2);
  __bf16* fin   = (__bf16*)alloc((size_t)2048 * 1024 * 2);
  float*  rbuf  = (float*)alloc((size_t)2048 * 512 * 4);
  float*  aProd = (float*)alloc((size_t)4 * NC * 16384 * 4);
  float*  hPart = (float*)alloc((size_t)4 * NC * 16384 * 4);
  float*  hInB  = (float*)alloc((size_t)4 * NC * 16384 * 4);
  (void)ws_size; (void)n_in; (void)in_sizes; (void)out_size;

  // 1) casts
  CastArgs ca;
  ca.s[0] = { x,        xbf,   (2048 * 512) / 4 };
  ca.s[1] = { f_in_w,   wInF,  (2048 * 512) / 4 };
  ca.s[2] = { b_in_w,   wInB,  (2048 * 512) / 4 };
  ca.s[3] = { f_xproj,  xprF,  (64 * 1024) / 4 };
  ca.s[4] = { b_xproj,  xprB,  (64 * 1024) / 4 };
  ca.s[5] = { f_out_w,  wOutF, (512 * 1024) / 4 };
  ca.s[6] = { b_out_w,  wOutB, (512 * 1024) / 4 };
  ca.s[7] = { fusion_w, wFus,  (512 * 1024) / 4 };
  cast_kernel<<<dim3(256, 8), 256, 0, stream>>>(ca);

  // 2) G1: xz[dir] = x @ in_w^T   (M=2048, N=2048, K=512)
  gemm_bt<float, false, false><<<dim3(16, 16, 2), 256, 0, stream>>>(
      xbf, 0LL, wInF, wInB, xzbuf, (long long)2048 * 2048, 2048, 2048, 512,
      nullptr, nullptr, 0);

  // 3) conv + SiLU -> xi (f32 + bf16)
  conv_silu_kernel<<<dim3(4, 8, 4), 256, 0, stream>>>(
      xzbuf, f_conv_w, f_conv_b, b_conv_w, b_conv_b, xi32, xi16);

  // 4) G2: x_dbl[dir] = xi @ xproj^T   (N=64, K=1024)
  gemm_bt<float, false, false><<<dim3(1, 16, 2), 256, 0, stream>>>(
      xi16, (long long)2048 * 1024, xprF, xprB, xdbl, (long long)2048 * 64, 64,
      64, 1024, nullptr, nullptr, 0);

  // 5) prep: delta -> {del, del*xi}; silu(z) in place; BC pack
  prep_kernel<<<dim3(4, 64, 2), 256, 0, stream>>>(
      xzbuf, xi32, xdbl, f_dt_w, f_dt_b, b_dt_w, b_dt_b, pack2);
  bcpack_kernel<<<dim3(256), 256, 0, stream>>>(xdbl, bcbuf);

  // 6) chunked scan: pass1 -> combine -> pass3
  scan_part1<<<dim3(64, NC, 4), 256, 0, stream>>>(
      pack2, bcbuf, f_A_log, b_A_log, aProd, hPart);
  scan_combine<<<dim3(256), 256, 0, stream>>>(aProd, hPart, hInB);
  scan_part3<<<dim3(64, NC, 4), 256, 0, stream>>>(
      pack2, bcbuf, xi32, xzbuf, f_A_log, f_D, b_A_log, b_D, hInB, ybf);

  // 7) G4: fused_in[:, dir*512:+512] = y @ out_w^T  (N=512, K=1024)
  gemm_bt<__bf16, false, false><<<dim3(4, 16, 2), 256, 0, stream>>>(
      ybf, (long long)2048 * 1024, wOutF, wOutB, fin, 512LL, 1024, 512, 1024,
      nullptr, nullptr, 0);

  // 8) G5: r = x + fused_in @ fusion_w^T + fusion_b  (N=512, K=1024)
  gemm_bt<float, true, true><<<dim3(4, 16, 1), 256, 0, stream>>>(
      fin, 0LL, wFus, wFus, rbuf, 0LL, 512, 512, 1024,
      fusion_b, x, 512);

  // 9) LayerNorm -> d_out
  ln_kernel<<<2048, 256, 0, stream>>>(rbuf, ln_g, ln_b, (float*)d_out);
}

// Round 4
// 442.128 us; speedup vs baseline: 2.0055x; 1.0314x over previous
//
#include <hip/hip_runtime.h>
#include <hip/hip_bf16.h>

// ---------------- types & helpers ----------------
typedef __bf16 bf16x8 __attribute__((ext_vector_type(8)));
typedef __bf16 bf16x4 __attribute__((ext_vector_type(4)));
typedef float  f32x4  __attribute__((ext_vector_type(4)));

#define LOG2E 1.44269504088896340f

static __device__ __forceinline__ unsigned short f2bf_bits(float f) {
  unsigned u = __builtin_bit_cast(unsigned, f);
  u = u + 0x7FFFu + ((u >> 16) & 1u);   // RNE
  return (unsigned short)(u >> 16);
}
static __device__ __forceinline__ __bf16 to_bf16(float f) {
  unsigned short s = f2bf_bits(f);
  return __builtin_bit_cast(__bf16, s);
}
static __device__ __forceinline__ float fast_sigmoid(float x) {
  return __builtin_amdgcn_rcpf(1.f + __builtin_amdgcn_exp2f(-LOG2E * x));
}
// DPP rotate-add within 16-lane rows: p += rot(p, k). CTRL = 0x120|k (ROW_ROR).
template<int CTRL>
static __device__ __forceinline__ float dpp_rot_add(float p) {
  int v = __builtin_amdgcn_update_dpp(0, __builtin_bit_cast(int, p), CTRL, 0xF, 0xF, false);
  return p + __builtin_bit_cast(float, v);
}

// ---------------- cast f32 -> bf16 (8 segments) ----------------
struct CastSeg { const float* src; __bf16* dst; int n4; };
struct CastArgs { CastSeg s[8]; };

__global__ __launch_bounds__(256) void cast_kernel(CastArgs a) {
  CastSeg seg = a.s[blockIdx.y];
  int idx = blockIdx.x * 256 + threadIdx.x;
  int stride = gridDim.x * 256;
  const float4* src = (const float4*)seg.src;
  bf16x4* dst = (bf16x4*)seg.dst;
  for (int i = idx; i < seg.n4; i += stride) {
    float4 v = src[i];
    bf16x4 o;
    o[0] = to_bf16(v.x); o[1] = to_bf16(v.y);
    o[2] = to_bf16(v.z); o[3] = to_bf16(v.w);
    dst[i] = o;
  }
}

// ---------------- GEMM: C[M,N] = A[M,K] @ B[N,K]^T (+bias)(+resid)(+silu) ---
template<typename OutT, bool BIAS, bool RESID, bool SILUHI>
__global__ __launch_bounds__(256) void gemm_bt(
    const __bf16* __restrict__ A, long long sAz,
    const __bf16* __restrict__ B0, const __bf16* __restrict__ B1,
    OutT* __restrict__ C, long long sCz, int ldc,
    int N, int K,
    const float* __restrict__ bias, const float* __restrict__ resid, int ldr,
    int siluFrom)
{
  const __bf16* B = (blockIdx.z == 0) ? B0 : B1;
  A += (size_t)blockIdx.z * (size_t)sAz;
  C += (size_t)blockIdx.z * (size_t)sCz;
  int lane = threadIdx.x & 63;
  int wid  = threadIdx.x >> 6;
  int rowBase = blockIdx.y * 128 + (wid >> 1) * 64;
  int colBase = blockIdx.x * 128 + (wid & 1) * 64;
  int lr = lane & 15;
  int lk = (lane >> 4) << 3;           // k-offset within 32-chunk
  const __bf16* Ap = A + (size_t)(rowBase + lr) * K + lk;
  const __bf16* Bp[4];
  #pragma unroll
  for (int ni = 0; ni < 4; ++ni) {
    int br = colBase + ni * 16 + lr;
    if (br > N - 1) br = N - 1;        // clamp (stores masked below)
    Bp[ni] = B + (size_t)br * K + lk;
  }
  f32x4 acc[4][4] = {};
  #pragma unroll 2
  for (int k = 0; k < K; k += 32) {
    bf16x8 aF[4], bF[4];
    #pragma unroll
    for (int mi = 0; mi < 4; ++mi)
      aF[mi] = *(const bf16x8*)(Ap + (size_t)(mi * 16) * K + k);
    #pragma unroll
    for (int ni = 0; ni < 4; ++ni)
      bF[ni] = *(const bf16x8*)(Bp[ni] + k);
    #pragma unroll
    for (int mi = 0; mi < 4; ++mi)
      #pragma unroll
      for (int ni = 0; ni < 4; ++ni)
        acc[mi][ni] = __builtin_amdgcn_mfma_f32_16x16x32_bf16(aF[mi], bF[ni], acc[mi][ni], 0, 0, 0);
  }
  int crow = rowBase + ((lane >> 4) << 2);
  int ccol = colBase + lr;
  #pragma unroll
  for (int mi = 0; mi < 4; ++mi) {
    #pragma unroll
    for (int ni = 0; ni < 4; ++ni) {
      int c = ccol + ni * 16;
      if (c < N) {
        #pragma unroll
        for (int j = 0; j < 4; ++j) {
          int r = crow + mi * 16 + j;
          float v = acc[mi][ni][j];
          if (BIAS)  v += bias[c];
          if (RESID) v += resid[(size_t)r * ldr + c];
          if (SILUHI && c >= siluFrom) v = v * fast_sigmoid(v);
          if constexpr (sizeof(OutT) == 2) C[(size_t)r * ldc + c] = to_bf16(v);
          else                             C[(size_t)r * ldc + c] = v;
        }
      }
    }
  }
}

// ---------------- causal depthwise conv (both directions) + SiLU ------------
__global__ __launch_bounds__(256) void conv_silu_kernel(
    const float* __restrict__ xz,     // [dir][2048][2048], xi = cols 0..1023
    const float* __restrict__ f_cw, const float* __restrict__ f_cb,
    const float* __restrict__ b_cw, const float* __restrict__ b_cb,
    float* __restrict__ xi32,         // [dir][2048][1024]
    __bf16* __restrict__ xi16)        // [dir][2048][1024]
{
  int d  = blockIdx.x * 256 + threadIdx.x;   // 0..1023
  int t0 = blockIdx.y * 128;
  int dir = blockIdx.z >> 1, b = blockIdx.z & 1;
  const float* cw = dir ? b_cw : f_cw;
  const float* cb = dir ? b_cb : f_cb;
  float w0 = cw[d*4+0], w1 = cw[d*4+1], w2 = cw[d*4+2], w3 = cw[d*4+3];
  float bias = cb[d];
  size_t rowBase = (size_t)dir * 2048 + (size_t)b * 1024;
  const float* xp = xz + rowBase * 2048 + d;
  float* o32 = xi32 + rowBase * 1024 + d;
  __bf16* o16 = xi16 + rowBase * 1024 + d;
  auto X = [&](int t) -> float {
    return (t >= 0 && t < 1024) ? xp[(size_t)t * 2048] : 0.f;
  };
  if (dir == 0) {
    float a = X(t0-3), bb = X(t0-2), c = X(t0-1);
    for (int t = t0; t < t0 + 128; ++t) {
      float cur = xp[(size_t)t * 2048];
      float v = fmaf(w0, a, fmaf(w1, bb, fmaf(w2, c, fmaf(w3, cur, bias))));
      float s = v * fast_sigmoid(v);
      o32[(size_t)t * 1024] = s;
      o16[(size_t)t * 1024] = to_bf16(s);
      a = bb; bb = c; c = cur;
    }
  } else {
    float a = X(t0), bb = X(t0+1), c = X(t0+2);
    for (int t = t0; t < t0 + 128; ++t) {
      float nx = X(t + 3);
      float v = fmaf(w3, a, fmaf(w2, bb, fmaf(w1, c, fmaf(w0, nx, bias))));
      float s = v * fast_sigmoid(v);
      o32[(size_t)t * 1024] = s;
      o16[(size_t)t * 1024] = to_bf16(s);
      a = bb; bb = c; c = nx;
    }
  }
}

// ---------------- prep: pack4 = {del, del*xi, xi*D*gate, gate} --------------
__global__ __launch_bounds__(256) void prep_kernel(
    const float* __restrict__ xz,     // [dir][2048][2048]; z-half already silu'd
    const float* __restrict__ xi32,   // [dir][2048][1024]
    const float* __restrict__ xdbl,   // [dir][2048][64], dt = cols 0..31
    const float* __restrict__ f_dtw, const float* __restrict__ f_dtb,
    const float* __restrict__ b_dtw, const float* __restrict__ b_dtb,
    const float* __restrict__ f_D, const float* __restrict__ b_D,
    float4* __restrict__ pack4)       // [dir][2048][1024]
{
  int d = blockIdx.x * 256 + threadIdx.x;
  int dir = blockIdx.z;
  const float* dtw = dir ? b_dtw : f_dtw;
  const float* dtb = dir ? b_dtb : f_dtb;
  float Dv = (dir ? b_D : f_D)[d];
  float w[32];
  #pragma unroll
  for (int k = 0; k < 32; ++k) w[k] = dtw[d * 32 + k];
  float bias = dtb[d];
  int row0 = dir * 2048 + blockIdx.y * 32;
  for (int r = 0; r < 32; ++r) {
    int row = row0 + r;
    const float4* xr = (const float4*)(xdbl + (size_t)row * 64);
    float acc = bias;
    #pragma unroll
    for (int q = 0; q < 8; ++q) {
      float4 v = xr[q];
      acc = fmaf(w[q*4+0], v.x, acc);
      acc = fmaf(w[q*4+1], v.y, acc);
      acc = fmaf(w[q*4+2], v.z, acc);
      acc = fmaf(w[q*4+3], v.w, acc);
    }
    float m = fmaxf(acc, 0.f);
    float e = __builtin_amdgcn_exp2f(-LOG2E * fabsf(acc));
    float del = fmaf(__builtin_amdgcn_logf(1.f + e), 1.f / LOG2E, m);
    float xi = xi32[(size_t)row * 1024 + d];
    float gate = xz[(size_t)row * 2048 + 1024 + d];
    pack4[(size_t)row * 1024 + d] = float4{del, del * xi, xi * Dv * gate, gate};
  }
}

// ---------------- BC pack: {B,C} contiguous per (row, n) --------------------
__global__ __launch_bounds__(256) void bcpack_kernel(
    const float* __restrict__ xdbl,   // [4096][64]
    float2* __restrict__ bc)          // [4096][16]
{
  int idx = blockIdx.x * 256 + threadIdx.x;  // 0..65535
  int row = idx >> 4, n = idx & 15;
  const float* src = xdbl + (size_t)row * 64;
  bc[idx] = float2{src[32 + n], src[48 + n]};
}

// ---------------- chunked parallel scan ------------------------------------
// h_t = a_t h_{t-1} + b_t, a_t = exp2(delta*As), b_t = (delta*xi)*B.
#define NC 32
#define CL 32

// pass1: per chunk from h=0: aProd = prod(a), hPart = partial state.
__global__ __launch_bounds__(256) void scan_part1(
    const float4* __restrict__ pack4, // [dir][2048][1024] {del, dx, xiDg, gate}
    const float2* __restrict__ bc,    // [4096][16] {B, C}
    const float* __restrict__ f_Alog, const float* __restrict__ b_Alog,
    float* __restrict__ aProd, float* __restrict__ hPart)  // [zb][NC][16384]
{
  int n = threadIdx.x & 15;
  int c = threadIdx.x >> 4;
  int d = blockIdx.x * 16 + c;
  int g = blockIdx.y;
  int zb = blockIdx.z;
  int dir = zb >> 1, b = zb & 1;
  const float* Alog = dir ? b_Alog : f_Alog;
  float As = -__builtin_amdgcn_exp2f(LOG2E * Alog[d * 16 + n]) * LOG2E;
  int base = dir * 2048 + b * 1024;
  int rowIdx0 = base + (dir ? (1023 - g * CL) : (g * CL));
  int rs = dir ? -1 : 1;
  int pIdx = rowIdx0 * 1024 + d, pS = rs * 1024;
  int qIdx = rowIdx0 * 16 + n,  qS = rs * 16;
  const float2* p2 = (const float2*)pack4;   // .xy at float2 index 2*idx
  const float* bcf = (const float*)bc;       // B at float index 2*idx

  float2 bp[3][4]; float bb[3][4];
  auto LOADG = [&](int bi, int gg) {
    #pragma unroll
    for (int j = 0; j < 4; ++j) {
      int t = gg * 4 + j;
      bp[bi][j] = p2[2 * (pIdx + t * pS)];
      bb[bi][j] = bcf[2 * (qIdx + t * qS)];
    }
  };
  LOADG(0, 0); LOADG(1, 1);
  float A = 1.f, H = 0.f;
  #pragma unroll
  for (int gg = 0; gg < CL / 4; ++gg) {
    if (gg + 2 < CL / 4) LOADG((gg + 2) % 3, gg + 2);
    #pragma unroll
    for (int j = 0; j < 4; ++j) {
      float2 v = bp[gg % 3][j];
      float Bv = bb[gg % 3][j];
      float dA = __builtin_amdgcn_exp2f(v.x * As);
      H = fmaf(dA, H, v.y * Bv);
      A *= dA;
    }
  }
  size_t o = ((size_t)zb * NC + g) * 16384 + (size_t)d * 16 + n;
  aProd[o] = A;
  hPart[o] = H;
}

// pass2: per (zb, d, n): serial over NC chunks -> incoming state per chunk.
__global__ __launch_bounds__(256) void scan_combine(
    const float* __restrict__ aProd, const float* __restrict__ hPart,
    float* __restrict__ hIn)
{
  int idx = blockIdx.x * 256 + threadIdx.x;   // 0..65535
  int zb = idx >> 14;
  int dn = idx & 16383;
  float a[NC], hp[NC];
  #pragma unroll
  for (int g = 0; g < NC; ++g) {
    size_t o = ((size_t)zb * NC + g) * 16384 + dn;
    a[g] = aProd[o];
    hp[g] = hPart[o];
  }
  float H = 0.f;
  #pragma unroll
  for (int g = 0; g < NC; ++g) {
    size_t o = ((size_t)zb * NC + g) * 16384 + dn;
    hIn[o] = H;
    H = fmaf(a[g], H, hp[g]);
  }
}

// pass3: re-scan chunk from hIn; C-dot via DPP rotate-add; per-lane y select:
// lane n keeps step (16G+n)'s reduced p, finalizes y = p*gate + xi*D*gate
// with ONE 8B gather + ONE store per 16 steps.
__global__ __launch_bounds__(256) void scan_part3(
    const float4* __restrict__ pack4, const float2* __restrict__ bc,
    const float* __restrict__ f_Alog, const float* __restrict__ b_Alog,
    const float* __restrict__ hIn,
    __bf16* __restrict__ yout)        // [dir][2048][1024]
{
  int n = threadIdx.x & 15;
  int c = threadIdx.x >> 4;
  int d = blockIdx.x * 16 + c;
  int g = blockIdx.y;
  int zb = blockIdx.z;
  int dir = zb >> 1, b = zb & 1;
  const float* Alog = dir ? b_Alog : f_Alog;
  float As = -__builtin_amdgcn_exp2f(LOG2E * Alog[d * 16 + n]) * LOG2E;
  int base = dir * 2048 + b * 1024;
  int rowIdx0 = base + (dir ? (1023 - g * CL) : (g * CL));
  int rs = dir ? -1 : 1;
  int pIdx = rowIdx0 * 1024 + d, pS = rs * 1024;
  int qIdx = rowIdx0 * 16 + n,  qS = rs * 16;
  const float2* p2 = (const float2*)pack4;
  int nOff = n * pS;                 // lane's row offset within a 16-step group
  int p16 = 16 * pS;

  float2 bp[3][4]; float2 bbc[3][4];
  auto LOADG = [&](int bi, int gg) {
    #pragma unroll
    for (int j = 0; j < 4; ++j) {
      int t = gg * 4 + j;
      bp[bi][j]  = p2[2 * (pIdx + t * pS)];
      bbc[bi][j] = bc[qIdx + t * qS];
    }
  };
  LOADG(0, 0); LOADG(1, 1);
  float h = hIn[((size_t)zb * NC + g) * 16384 + (size_t)d * 16 + n];
  float psel = 0.f;
  #pragma unroll
  for (int gg = 0; gg < CL / 4; ++gg) {
    if (gg + 2 < CL / 4) LOADG((gg + 2) % 3, gg + 2);
    #pragma unroll
    for (int j = 0; j < 4; ++j) {
      int t = gg * 4 + j;
      float2 v = bp[gg % 3][j];
      float2 w2 = bbc[gg % 3][j];
      float dA = __builtin_amdgcn_exp2f(v.x * As);
      h = fmaf(dA, h, v.y * w2.x);
      float p = h * w2.y;
      p = dpp_rot_add<0x121>(p);   // row_ror:1
      p = dpp_rot_add<0x122>(p);   // row_ror:2
      p = dpp_rot_add<0x124>(p);   // row_ror:4
      p = dpp_rot_add<0x128>(p);   // row_ror:8
      psel = (n == (t & 15)) ? p : psel;
      if ((t & 15) == 15) {
        int G = t >> 4;
        int idxF = pIdx + G * p16 + nOff;       // row(16G+n)*1024 + d
        float2 zw = p2[2 * idxF + 1];           // {xi*D*gate, gate}
        float y = fmaf(psel, zw.y, zw.x);
        yout[idxF] = to_bf16(y);
      }
    }
  }
}

// ---------------- LayerNorm over last dim (512) -----------------------------
__global__ __launch_bounds__(256) void ln_kernel(
    const float* __restrict__ r, const float* __restrict__ g,
    const float* __restrict__ beta, float* __restrict__ out)
{
  int row = blockIdx.x;
  int tid = threadIdx.x;
  const float* rp = r + (size_t)row * 512;
  float v0 = rp[tid], v1 = rp[tid + 256];
  float s = v0 + v1;
  float q = fmaf(v0, v0, v1 * v1);
  #pragma unroll
  for (int m = 1; m < 64; m <<= 1) {
    s += __shfl_xor(s, m, 64);
    q += __shfl_xor(q, m, 64);
  }
  __shared__ float ls[4], lq[4];
  int wid = tid >> 6;
  if ((tid & 63) == 0) { ls[wid] = s; lq[wid] = q; }
  __syncthreads();
  s = ls[0] + ls[1] + ls[2] + ls[3];
  q = lq[0] + lq[1] + lq[2] + lq[3];
  float mu = s * (1.f / 512.f);
  float var = q * (1.f / 512.f) - mu * mu;
  float rs = rsqrtf(var + 1e-5f);
  float* op = out + (size_t)row * 512;
  op[tid]       = (v0 - mu) * rs * g[tid]       + beta[tid];
  op[tid + 256] = (v1 - mu) * rs * g[tid + 256] + beta[tid + 256];
}

// ---------------- host launch ----------------
extern "C" void kernel_launch(void* const* d_in, const int* in_sizes, int n_in,
                              void* d_out, int out_size, void* d_ws, size_t ws_size,
                              hipStream_t stream)
{
  const float* x        = (const float*)d_in[0];
  const float* fusion_w = (const float*)d_in[1];
  const float* fusion_b = (const float*)d_in[2];
  const float* ln_g     = (const float*)d_in[3];
  const float* ln_b     = (const float*)d_in[4];
  const float* f_in_w   = (const float*)d_in[5];
  const float* f_conv_w = (const float*)d_in[6];
  const float* f_conv_b = (const float*)d_in[7];
  const float* f_xproj  = (const float*)d_in[8];
  const float* f_dt_w   = (const float*)d_in[9];
  const float* f_dt_b   = (const float*)d_in[10];
  const float* f_A_log  = (const float*)d_in[11];
  const float* f_D      = (const float*)d_in[12];
  const float* f_out_w  = (const float*)d_in[13];
  const float* b_in_w   = (const float*)d_in[14];
  const float* b_conv_w = (const float*)d_in[15];
  const float* b_conv_b = (const float*)d_in[16];
  const float* b_xproj  = (const float*)d_in[17];
  const float* b_dt_w   = (const float*)d_in[18];
  const float* b_dt_b   = (const float*)d_in[19];
  const float* b_A_log  = (const float*)d_in[20];
  const float* b_D      = (const float*)d_in[21];
  const float* b_out_w  = (const float*)d_in[22];

  char* w = (char*)d_ws;
  auto alloc = [&](size_t bytes) -> char* {
    char* p = w;
    w += (bytes + 255) & ~(size_t)255;
    return p;
  };
  __bf16* xbf   = (__bf16*)alloc((size_t)2048 * 512 * 2);
  __bf16* wInF  = (__bf16*)alloc((size_t)2048 * 512 * 2);
  __bf16* wInB  = (__bf16*)alloc((size_t)2048 * 512 * 2);
  __bf16* xprF  = (__bf16*)alloc((size_t)64 * 1024 * 2);
  __bf16* xprB  = (__bf16*)alloc((size_t)64 * 1024 * 2);
  __bf16* wOutF = (__bf16*)alloc((size_t)512 * 1024 * 2);
  __bf16* wOutB = (__bf16*)alloc((size_t)512 * 1024 * 2);
  __bf16* wFus  = (__bf16*)alloc((size_t)512 * 1024 * 2);
  float*  xzbuf = (float*)alloc((size_t)2 * 2048 * 2048 * 4);
  float*  xi32  = (float*)alloc((size_t)2 * 2048 * 1024 * 4);
  __bf16* xi16  = (__bf16*)alloc((size_t)2 * 2048 * 1024 * 2);
  float*  xdbl  = (float*)alloc((size_t)2 * 2048 * 64 * 4);
  float4* pack4 = (float4*)alloc((size_t)2 * 2048 * 1024 * 16);
  float2* bcbuf = (float2*)alloc((size_t)4096 * 16 * 8);
  __bf16* ybf   = (__bf16*)alloc((size_t)2 * 2048 * 1024 * 2);
  __bf16* fin   = (__bf16*)alloc((size_t)2048 * 1024 * 2);
  float*  rbuf  = (float*)alloc((size_t)2048 * 512 * 4);
  float*  aProd = (float*)alloc((size_t)4 * NC * 16384 * 4);
  float*  hPart = (float*)alloc((size_t)4 * NC * 16384 * 4);
  float*  hInB  = (float*)alloc((size_t)4 * NC * 16384 * 4);
  (void)ws_size; (void)n_in; (void)in_sizes; (void)out_size;

  // 1) casts
  CastArgs ca;
  ca.s[0] = { x,        xbf,   (2048 * 512) / 4 };
  ca.s[1] = { f_in_w,   wInF,  (2048 * 512) / 4 };
  ca.s[2] = { b_in_w,   wInB,  (2048 * 512) / 4 };
  ca.s[3] = { f_xproj,  xprF,  (64 * 1024) / 4 };
  ca.s[4] = { b_xproj,  xprB,  (64 * 1024) / 4 };
  ca.s[5] = { f_out_w,  wOutF, (512 * 1024) / 4 };
  ca.s[6] = { b_out_w,  wOutB, (512 * 1024) / 4 };
  ca.s[7] = { fusion_w, wFus,  (512 * 1024) / 4 };
  cast_kernel<<<dim3(256, 8), 256, 0, stream>>>(ca);

  // 2) G1: xz[dir] = x @ in_w^T (M=2048, N=2048, K=512); silu on z-half cols
  gemm_bt<float, false, false, true><<<dim3(16, 16, 2), 256, 0, stream>>>(
      xbf, 0LL, wInF, wInB, xzbuf, (long long)2048 * 2048, 2048, 2048, 512,
      nullptr, nullptr, 0, 1024);

  // 3) conv + SiLU -> xi (f32 + bf16)
  conv_silu_kernel<<<dim3(4, 8, 4), 256, 0, stream>>>(
      xzbuf, f_conv_w, f_conv_b, b_conv_w, b_conv_b, xi32, xi16);

  // 4) G2: x_dbl[dir] = xi @ xproj^T   (N=64, K=1024)
  gemm_bt<float, false, false, false><<<dim3(1, 16, 2), 256, 0, stream>>>(
      xi16, (long long)2048 * 1024, xprF, xprB, xdbl, (long long)2048 * 64, 64,
      64, 1024, nullptr, nullptr, 0, 0);

  // 5) prep: pack4 = {del, del*xi, xi*D*gate, gate}; BC pack
  prep_kernel<<<dim3(4, 64, 2), 256, 0, stream>>>(
      xzbuf, xi32, xdbl, f_dt_w, f_dt_b, b_dt_w, b_dt_b, f_D, b_D, pack4);
  bcpack_kernel<<<dim3(256), 256, 0, stream>>>(xdbl, bcbuf);

  // 6) chunked scan: pass1 -> combine -> pass3
  scan_part1<<<dim3(64, NC, 4), 256, 0, stream>>>(
      pack4, bcbuf, f_A_log, b_A_log, aProd, hPart);
  scan_combine<<<dim3(256), 256, 0, stream>>>(aProd, hPart, hInB);
  scan_part3<<<dim3(64, NC, 4), 256, 0, stream>>>(
      pack4, bcbuf, f_A_log, b_A_log, hInB, ybf);

  // 7) G4: fused_in[:, dir*512:+512] = y @ out_w^T  (N=512, K=1024)
  gemm_bt<__bf16, false, false, false><<<dim3(4, 16, 2), 256, 0, stream>>>(
      ybf, (long long)2048 * 1024, wOutF, wOutB, fin, 512LL, 1024, 512, 1024,
      nullptr, nullptr, 0, 0);

  // 8) G5: r = x + fused_in @ fusion_w^T + fusion_b  (N=512, K=1024)
  gemm_bt<float, true, true, false><<<dim3(4, 16, 1), 256, 0, stream>>>(
      fin, 0LL, wFus, wFus, rbuf, 0LL, 512, 512, 1024,
      fusion_b, x, 512, 0);

  // 9) LayerNorm -> d_out
  ln_kernel<<<2048, 256, 0, stream>>>(rbuf, ln_g, ln_b, (float*)d_out);
}